// Round 1
// baseline (433.447 us; speedup 1.0000x reference)
//
#include <hip/hip_runtime.h>

typedef unsigned short u16;
typedef short short8 __attribute__((ext_vector_type(8)));
typedef float f32x4 __attribute__((ext_vector_type(4)));

#define NTOK 2009
#define M8   8036      // 4*2009
#define DMOD 1024
#define VROW 2016      // padded Vt row (k dim), multiple of 32
#define SROW 2020      // padded LDS score row; 2020%32=4 -> bank rotate

static __device__ __forceinline__ u16 f2bf(float f) {
  unsigned int x = __float_as_uint(f);
  x += 0x7fffu + ((x >> 16) & 1u);
  return (u16)(x >> 16);
}
static __device__ __forceinline__ float bf2f(u16 u) {
  return __uint_as_float((unsigned int)u << 16);
}

// ---------------- converts ----------------
__global__ void k_conv_x(const float* __restrict__ x, u16* __restrict__ xb) {
  int i = blockIdx.x * 256 + threadIdx.x;          // 2,057,216 float4s
  float4 v = ((const float4*)x)[i];
  unsigned int a = (unsigned int)f2bf(v.x) | ((unsigned int)f2bf(v.y) << 16);
  unsigned int b = (unsigned int)f2bf(v.z) | ((unsigned int)f2bf(v.w) << 16);
  ((uint2*)xb)[i] = make_uint2(a, b);
}

__global__ void k_conv_wcat(const float* __restrict__ Wqkv, const float* __restrict__ Wqs,
                            u16* __restrict__ WtCat) {
  int i = blockIdx.x * 256 + threadIdx.x;          // 1280*1024
  int n = i >> 10, k = i & 1023;
  float v = (n < 768) ? Wqkv[k * 768 + n] : Wqs[k * 512 + (n - 768)];
  WtCat[i] = f2bf(v);
}

__global__ void k_conv_wout(const float* __restrict__ Wout, u16* __restrict__ WtOut) {
  int i = blockIdx.x * 256 + threadIdx.x;          // 1024*256
  int n = i >> 8, k = i & 255;
  WtOut[i] = f2bf(Wout[k * 1024 + n]);
}

// ---------------- projection GEMM: [8036,1024] x [1280,1024]^T ----------------
// scatters into per-head Q/K/Qs/Ks [bh][tok][64] and Vt [bh][64][VROW]
__global__ __launch_bounds__(256) void k_gemm_proj(
    const u16* __restrict__ A, const u16* __restrict__ Bt,
    u16* __restrict__ Qb, u16* __restrict__ Kb, u16* __restrict__ Vt,
    u16* __restrict__ Qsb, u16* __restrict__ Ksb)
{
  const int K = 1024;
  __shared__ u16 Al[64][72];
  __shared__ u16 Bl[64][72];
  int mt = blockIdx.x * 64, nt = blockIdx.y * 64;
  int tid = threadIdx.x; int lane = tid & 63, wave = tid >> 6;
  int fr = lane & 15, fk = (lane >> 4) * 8;
  f32x4 acc[4];
#pragma unroll
  for (int i = 0; i < 4; ++i) acc[i] = (f32x4){0.f, 0.f, 0.f, 0.f};
  for (int kt = 0; kt < K; kt += 64) {
#pragma unroll
    for (int r = 0; r < 2; ++r) {
      int c = tid + r * 256;
      int row = c >> 3, ch = (c & 7) * 8;
      int am = mt + row; if (am >= M8) am = 0;
      *(short8*)&Al[row][ch] = *(const short8*)&A[(size_t)am * K + kt + ch];
      *(short8*)&Bl[row][ch] = *(const short8*)&Bt[(size_t)(nt + row) * K + kt + ch];
    }
    __syncthreads();
#pragma unroll
    for (int cs = 0; cs < 2; ++cs) {
      short8 bfr = *(const short8*)&Bl[wave * 16 + fr][cs * 32 + fk];
#pragma unroll
      for (int mi = 0; mi < 4; ++mi) {
        short8 afr = *(const short8*)&Al[mi * 16 + fr][cs * 32 + fk];
        acc[mi] = __builtin_amdgcn_mfma_f32_16x16x32_bf16(afr, bfr, acc[mi], 0, 0, 0);
      }
    }
    __syncthreads();
  }
  int n = nt + wave * 16 + fr;
  int g = n >> 6, d = n & 63;
  int h = g & 3, sel = g >> 2;   // 0=q 1=k 2=v 3=qs 4=ks
  u16* p = (sel == 0) ? Qb : (sel == 1) ? Kb : (sel == 3) ? Qsb : Ksb;
#pragma unroll
  for (int mi = 0; mi < 4; ++mi) {
#pragma unroll
    for (int i = 0; i < 4; ++i) {
      int m = mt + mi * 16 + (lane >> 4) * 4 + i;
      if (m >= M8) continue;
      int b_ = m / NTOK, tok = m - b_ * NTOK;
      int bh = b_ * 4 + h;
      u16 val = f2bf(acc[mi][i]);
      if (sel == 2) Vt[((size_t)bh * 64 + d) * VROW + tok] = val;
      else          p[((size_t)bh * NTOK + tok) * 64 + d] = val;
    }
  }
}

// ---------------- block-diagonal self dots ----------------
__global__ void k_self(const u16* __restrict__ Qs, const u16* __restrict__ Ks,
                       float* __restrict__ selfS) {
  int blk = blockIdx.x;            // bh*200 + agent
  int bh = blk / 200, a = blk % 200;
  int t = threadIdx.x;
  if (t >= 100) return;
  int ri = t / 10, rj = t % 10;
  const u16* qp = &Qs[((size_t)bh * NTOK + a * 10 + ri) * 64];
  const u16* kp = &Ks[((size_t)bh * NTOK + a * 10 + rj) * 64];
  float s = 0.f;
#pragma unroll 8
  for (int k = 0; k < 64; ++k) s += bf2f(qp[k]) * bf2f(kp[k]);
  selfS[(size_t)blk * 100 + t] = s * 0.0625f;
}

// ---------------- fused attention: 16 rows / WG ----------------
__global__ __launch_bounds__(256) void k_attn(
    const u16* __restrict__ Qb, const u16* __restrict__ Kb,
    const u16* __restrict__ Vt, const float* __restrict__ selfS,
    float* __restrict__ attn, u16* __restrict__ Ob)
{
  __shared__ float S[16][SROW];    // 129,280 B
  int bh = blockIdx.y;
  int r0 = blockIdx.x * 16;
  int tid = threadIdx.x, lane = tid & 63, wave = tid >> 6;
  int fr = lane & 15, fk = (lane >> 4) * 8;

  // Q fragments (rows r0..r0+15, clamped), reused across all col tiles
  int qrow = r0 + fr; if (qrow > NTOK - 1) qrow = NTOK - 1;
  const u16* qp = &Qb[((size_t)bh * NTOK + qrow) * 64];
  short8 aq0 = *(const short8*)&qp[fk];
  short8 aq1 = *(const short8*)&qp[32 + fk];

  // S = Q K^T * scale  (32 col tiles of 64; wave handles 16 cols)
  for (int ct = 0; ct < 32; ++ct) {
    int col = ct * 64 + wave * 16 + fr;
    int ccl = col > NTOK - 1 ? NTOK - 1 : col;
    const u16* kp = &Kb[((size_t)bh * NTOK + ccl) * 64];
    short8 b0 = *(const short8*)&kp[fk];
    short8 b1 = *(const short8*)&kp[32 + fk];
    f32x4 c = (f32x4){0.f, 0.f, 0.f, 0.f};
    c = __builtin_amdgcn_mfma_f32_16x16x32_bf16(aq0, b0, c, 0, 0, 0);
    c = __builtin_amdgcn_mfma_f32_16x16x32_bf16(aq1, b1, c, 0, 0, 0);
    if (col < NTOK) {
#pragma unroll
      for (int i = 0; i < 4; ++i)
        S[(lane >> 4) * 4 + i][col] = c[i] * 0.0625f;
    }
  }
  __syncthreads();

  // patch block-diagonal with self dots (rows <2000 only; cols within own agent)
  if (tid < 160) {
    int r = tid / 10, j = tid % 10;
    int grow = r0 + r;
    if (grow < 2000) {
      int a = grow / 10;
      S[r][a * 10 + j] = selfS[((size_t)bh * 200 + a) * 100 + (grow - a * 10) * 10 + j];
    }
  }
  // zero the k-pad region [2009, SROW) so PV tail contributes nothing
  if (tid < 176) {
    int r = tid / 11, c = NTOK + tid % 11;
    S[r][c] = 0.f;
  }
  __syncthreads();

  // softmax: each 16-lane group owns one row
  {
    int row = wave * 4 + (lane >> 4), sl = lane & 15;
    float m = -1e30f;
    for (int c2 = sl; c2 < NTOK; c2 += 16) m = fmaxf(m, S[row][c2]);
#pragma unroll
    for (int o = 8; o; o >>= 1) m = fmaxf(m, __shfl_xor(m, o));
    float s = 0.f;
    for (int c2 = sl; c2 < NTOK; c2 += 16) {
      float e = __expf(S[row][c2] - m);
      S[row][c2] = e; s += e;
    }
#pragma unroll
    for (int o = 8; o; o >>= 1) s += __shfl_xor(s, o);
    float inv = 1.f / s;
    for (int c2 = sl; c2 < NTOK; c2 += 16) S[row][c2] *= inv;
  }
  __syncthreads();

  // write attn rows (coalesced)
  for (int r = 0; r < 16; ++r) {
    int grow = r0 + r;
    if (grow >= NTOK) break;
    float* dst = &attn[((size_t)bh * NTOK + grow) * NTOK];
    for (int c2 = tid; c2 < NTOK; c2 += 256) dst[c2] = S[r][c2];
  }

  // PV: O[16,64] = P[16,2009] @ V ; wave handles 16 of the 64 d-cols
  {
    f32x4 o = (f32x4){0.f, 0.f, 0.f, 0.f};
    int d = wave * 16 + fr;
    const u16* vp = &Vt[((size_t)bh * 64 + d) * VROW + fk];
    const float* sp = &S[fr][fk];
    for (int kc = 0; kc < 63; ++kc) {
      const float* s8 = sp + kc * 32;
      short8 a;
#pragma unroll
      for (int e = 0; e < 8; ++e) a[e] = (short)f2bf(s8[e]);
      short8 bv = *(const short8*)&vp[kc * 32];
      o = __builtin_amdgcn_mfma_f32_16x16x32_bf16(a, bv, o, 0, 0, 0);
    }
    int b_ = bh >> 2, h = bh & 3;
#pragma unroll
    for (int i = 0; i < 4; ++i) {
      int grow = r0 + (lane >> 4) * 4 + i;
      if (grow < NTOK)
        Ob[((size_t)(b_ * NTOK + grow)) * 256 + h * 64 + d] = f2bf(o[i]);
    }
  }
}

// ---------------- output GEMM: [8036,256] x [1024,256]^T + bias ----------------
__global__ __launch_bounds__(256) void k_gemm_out(
    const u16* __restrict__ A, const u16* __restrict__ Bt,
    const float* __restrict__ bias, float* __restrict__ C)
{
  const int K = 256;
  __shared__ u16 Al[64][72];
  __shared__ u16 Bl[64][72];
  int mt = blockIdx.x * 64, nt = blockIdx.y * 64;
  int tid = threadIdx.x; int lane = tid & 63, wave = tid >> 6;
  int fr = lane & 15, fk = (lane >> 4) * 8;
  f32x4 acc[4];
#pragma unroll
  for (int i = 0; i < 4; ++i) acc[i] = (f32x4){0.f, 0.f, 0.f, 0.f};
  for (int kt = 0; kt < K; kt += 64) {
#pragma unroll
    for (int r = 0; r < 2; ++r) {
      int c = tid + r * 256;
      int row = c >> 3, ch = (c & 7) * 8;
      int am = mt + row; if (am >= M8) am = 0;
      *(short8*)&Al[row][ch] = *(const short8*)&A[(size_t)am * K + kt + ch];
      *(short8*)&Bl[row][ch] = *(const short8*)&Bt[(size_t)(nt + row) * K + kt + ch];
    }
    __syncthreads();
#pragma unroll
    for (int cs = 0; cs < 2; ++cs) {
      short8 bfr = *(const short8*)&Bl[wave * 16 + fr][cs * 32 + fk];
#pragma unroll
      for (int mi = 0; mi < 4; ++mi) {
        short8 afr = *(const short8*)&Al[mi * 16 + fr][cs * 32 + fk];
        acc[mi] = __builtin_amdgcn_mfma_f32_16x16x32_bf16(afr, bfr, acc[mi], 0, 0, 0);
      }
    }
    __syncthreads();
  }
  int n = nt + wave * 16 + fr;
  float bn = bias[n];
#pragma unroll
  for (int mi = 0; mi < 4; ++mi) {
#pragma unroll
    for (int i = 0; i < 4; ++i) {
      int m = mt + mi * 16 + (lane >> 4) * 4 + i;
      if (m < M8) C[(size_t)m * DMOD + n] = acc[mi][i] + bn;
    }
  }
}

extern "C" void kernel_launch(void* const* d_in, const int* in_sizes, int n_in,
                              void* d_out, int out_size, void* d_ws, size_t ws_size,
                              hipStream_t stream) {
  (void)in_sizes; (void)n_in; (void)out_size; (void)ws_size;
  const float* x    = (const float*)d_in[0];
  const float* Wqkv = (const float*)d_in[1];
  const float* Wqs  = (const float*)d_in[2];
  const float* Wout = (const float*)d_in[3];
  const float* bout = (const float*)d_in[4];
  float* out  = (float*)d_out;
  float* attn = out + (size_t)M8 * DMOD;          // 8,228,864 floats offset

  char* ws = (char*)d_ws;
  u16*   xb    = (u16*)(ws);                      // 16,457,728
  u16*   WtCat = (u16*)(ws + 16457728);           //  2,621,440
  u16*   WtOut = (u16*)(ws + 19079168);           //    524,288
  u16*   Qb    = (u16*)(ws + 19603456);           //  4,114,432
  u16*   Kb    = (u16*)(ws + 23717888);           //  4,114,432
  u16*   Qsb   = (u16*)(ws + 27832320);           //  4,114,432
  u16*   Ksb   = (u16*)(ws + 31946752);           //  4,114,432
  u16*   Vt    = (u16*)(ws + 36061184);           //  4,128,768
  u16*   Ob    = (u16*)(ws + 40189952);           //  4,114,432
  float* selfS = (float*)(ws + 44304384);         //  1,280,000  (total ~45.6 MB)

  k_conv_x<<<dim3(8036), dim3(256), 0, stream>>>(x, xb);
  k_conv_wcat<<<dim3(5120), dim3(256), 0, stream>>>(Wqkv, Wqs, WtCat);
  k_conv_wout<<<dim3(1024), dim3(256), 0, stream>>>(Wout, WtOut);
  k_gemm_proj<<<dim3(126, 20), dim3(256), 0, stream>>>(xb, WtCat, Qb, Kb, Vt, Qsb, Ksb);
  k_self<<<dim3(3200), dim3(128), 0, stream>>>(Qsb, Ksb, selfS);
  k_attn<<<dim3(126, 16), dim3(256), 0, stream>>>(Qb, Kb, Vt, selfS, attn, Ob);
  k_gemm_out<<<dim3(126, 16), dim3(256), 0, stream>>>(Ob, WtOut, bout, out);
}

// Round 2
// 261.133 us; speedup vs baseline: 1.6599x; 1.6599x over previous
//
#include <hip/hip_runtime.h>

typedef unsigned short u16;
typedef unsigned int u32;
typedef short short8 __attribute__((ext_vector_type(8)));
typedef float f32x4 __attribute__((ext_vector_type(4)));
typedef float f32x16 __attribute__((ext_vector_type(16)));
typedef float float4a __attribute__((ext_vector_type(4), aligned(4)));

#define NTOK 2009
#define M8   8036      // 4*2009
#define DMOD 1024
#define VROW 2016      // padded Vt row (k dim), multiple of 32

static __device__ __forceinline__ u16 f2bf(float f) {
  unsigned int x = __float_as_uint(f);
  x += 0x7fffu + ((x >> 16) & 1u);
  return (u16)(x >> 16);
}
static __device__ __forceinline__ float bf2f(u16 u) {
  return __uint_as_float((unsigned int)u << 16);
}
static __device__ __forceinline__ u32 pk2(float a, float b) {
  return (u32)f2bf(a) | ((u32)f2bf(b) << 16);
}

// ---------------- converts ----------------
__global__ void k_conv_x(const float* __restrict__ x, u16* __restrict__ xb) {
  int i = blockIdx.x * 256 + threadIdx.x;
  float4 v = ((const float4*)x)[i];
  unsigned int a = (unsigned int)f2bf(v.x) | ((unsigned int)f2bf(v.y) << 16);
  unsigned int b = (unsigned int)f2bf(v.z) | ((unsigned int)f2bf(v.w) << 16);
  ((uint2*)xb)[i] = make_uint2(a, b);
}

__global__ void k_conv_wcat(const float* __restrict__ Wqkv, const float* __restrict__ Wqs,
                            u16* __restrict__ WtCat) {
  int i = blockIdx.x * 256 + threadIdx.x;
  int n = i >> 10, k = i & 1023;
  float v = (n < 768) ? Wqkv[k * 768 + n] : Wqs[k * 512 + (n - 768)];
  WtCat[i] = f2bf(v);
}

__global__ void k_conv_wout(const float* __restrict__ Wout, u16* __restrict__ WtOut) {
  int i = blockIdx.x * 256 + threadIdx.x;
  int n = i >> 8, k = i & 255;
  WtOut[i] = f2bf(Wout[k * 1024 + n]);
}

// ---------------- projection GEMM: [8036,1024] x [1280,1024]^T ----------------
// scatters into per-head Q/K/Qs/Ks [bh][tok][64] and Vt [bh][64][VROW]
// Q and Qs are pre-scaled by head_dim^-0.5 = 1/16.
__global__ __launch_bounds__(256) void k_gemm_proj(
    const u16* __restrict__ A, const u16* __restrict__ Bt,
    u16* __restrict__ Qb, u16* __restrict__ Kb, u16* __restrict__ Vt,
    u16* __restrict__ Qsb, u16* __restrict__ Ksb)
{
  const int K = 1024;
  __shared__ u16 Al[64][72];
  __shared__ u16 Bl[64][72];
  int mt = blockIdx.x * 64, nt = blockIdx.y * 64;
  int tid = threadIdx.x; int lane = tid & 63, wave = tid >> 6;
  int fr = lane & 15, fk = (lane >> 4) * 8;
  f32x4 acc[4];
#pragma unroll
  for (int i = 0; i < 4; ++i) acc[i] = (f32x4){0.f, 0.f, 0.f, 0.f};
  for (int kt = 0; kt < K; kt += 64) {
#pragma unroll
    for (int r = 0; r < 2; ++r) {
      int c = tid + r * 256;
      int row = c >> 3, ch = (c & 7) * 8;
      int am = mt + row; if (am >= M8) am = 0;
      *(short8*)&Al[row][ch] = *(const short8*)&A[(size_t)am * K + kt + ch];
      *(short8*)&Bl[row][ch] = *(const short8*)&Bt[(size_t)(nt + row) * K + kt + ch];
    }
    __syncthreads();
#pragma unroll
    for (int cs = 0; cs < 2; ++cs) {
      short8 bfr = *(const short8*)&Bl[wave * 16 + fr][cs * 32 + fk];
#pragma unroll
      for (int mi = 0; mi < 4; ++mi) {
        short8 afr = *(const short8*)&Al[mi * 16 + fr][cs * 32 + fk];
        acc[mi] = __builtin_amdgcn_mfma_f32_16x16x32_bf16(afr, bfr, acc[mi], 0, 0, 0);
      }
    }
    __syncthreads();
  }
  int n = nt + wave * 16 + fr;
  int g = n >> 6, d = n & 63;
  int h = g & 3, sel = g >> 2;   // 0=q 1=k 2=v 3=qs 4=ks
  u16* p = (sel == 0) ? Qb : (sel == 1) ? Kb : (sel == 3) ? Qsb : Ksb;
  float scl = (sel == 0 || sel == 3) ? 0.0625f : 1.0f;
#pragma unroll
  for (int mi = 0; mi < 4; ++mi) {
#pragma unroll
    for (int i = 0; i < 4; ++i) {
      int m = mt + mi * 16 + (lane >> 4) * 4 + i;
      if (m >= M8) continue;
      int b_ = m / NTOK, tok = m - b_ * NTOK;
      int bh = b_ * 4 + h;
      u16 val = f2bf(acc[mi][i] * scl);
      if (sel == 2) Vt[((size_t)bh * 64 + d) * VROW + tok] = val;
      else          p[((size_t)bh * NTOK + tok) * 64 + d] = val;
    }
  }
}

// ---------------- block-diagonal self dots (Qs pre-scaled) ----------------
__global__ void k_self(const u16* __restrict__ Qs, const u16* __restrict__ Ks,
                       float* __restrict__ selfS) {
  int blk = blockIdx.x;            // bh*200 + agent
  int bh = blk / 200, a = blk % 200;
  int t = threadIdx.x;
  if (t >= 100) return;
  int ri = t / 10, rj = t % 10;
  const u16* qp = &Qs[((size_t)bh * NTOK + a * 10 + ri) * 64];
  const u16* kp = &Ks[((size_t)bh * NTOK + a * 10 + rj) * 64];
  float s = 0.f;
#pragma unroll 8
  for (int k = 0; k < 64; ++k) s += bf2f(qp[k]) * bf2f(kp[k]);
  selfS[(size_t)blk * 100 + t] = s;
}

// ---------------- fused attention, two-pass, swapped 32x32 MFMA ----------------
// 1 wave per 32 q-rows. Pass 1: sum of exp (max-free; scores are O(1)).
// Pass 2: recompute scores, write normalized attn, PV into O^T[d][q].
__global__ __launch_bounds__(64) void k_attn2(
    const u16* __restrict__ Qb, const u16* __restrict__ Kb,
    const u16* __restrict__ Vt, const float* __restrict__ selfS,
    float* __restrict__ attn, u16* __restrict__ Ob)
{
  int bh = blockIdx.x;
  int q0 = blockIdx.y * 32;
  int lane = threadIdx.x;
  int ql = lane & 31, h = lane >> 5;
  int qg = q0 + ql;
  bool qok = qg < NTOK;
  int qc = qok ? qg : NTOK - 1;

  const u16* qp = &Qb[((size_t)bh * NTOK + qc) * 64];
  short8 qf[4];
#pragma unroll
  for (int c = 0; c < 4; ++c) qf[c] = *(const short8*)&qp[16 * c + 8 * h];

  // block-diagonal patch band for this wave's rows
  int qa = (qg < 2000) ? (qg / 10) : -1;          // this row's agent (or none)
  int band_lo = 1 << 30, band_hi = -(1 << 30);
  if (q0 < 2000) {
    int hi_row = (q0 + 31 < 1999) ? q0 + 31 : 1999;
    band_lo = (q0 / 10) * 10;
    band_hi = (hi_row / 10) * 10 + 10;
  }
  const float* sfb = &selfS[(size_t)bh * 20000];

  const u16* kbase = &Kb[(size_t)bh * NTOK * 64];
  const u16* vbase = &Vt[(size_t)bh * 64 * VROW];

  short8 kf[4], kfn[4];

  // ================= pass 1: row sums of exp =================
  {
    int kr0 = ql;  // tile kt=0 rows
#pragma unroll
    for (int c = 0; c < 4; ++c)
      kf[c] = *(const short8*)&kbase[(size_t)kr0 * 64 + 16 * c + 8 * h];
  }
  float ssum = 0.f;
  for (int kt = 0; kt < 2016; kt += 32) {
    {
      int ktn = (kt + 32 < 2016) ? kt + 32 : 0;
      int kr = ktn + ql; if (kr >= NTOK) kr = NTOK - 1;
#pragma unroll
      for (int c = 0; c < 4; ++c)
        kfn[c] = *(const short8*)&kbase[(size_t)kr * 64 + 16 * c + 8 * h];
    }
    f32x16 acc = {};
#pragma unroll
    for (int c = 0; c < 4; ++c)
      acc = __builtin_amdgcn_mfma_f32_32x32x16_bf16(kf[c], qf[c], acc, 0, 0, 0);
    bool mayPatch = (kt < band_hi) && (kt + 32 > band_lo);
#pragma unroll
    for (int r = 0; r < 16; ++r) {
      int kc = kt + (r & 3) + 8 * (r >> 2) + 4 * h;
      float sc = acc[r];
      if (mayPatch) {
        if (qa >= 0 && kc < 2000 && (kc / 10) == qa)
          sc = sfb[qa * 100 + (qg - qa * 10) * 10 + (kc - qa * 10)];
      }
      ssum += (kc < NTOK) ? __expf(sc) : 0.f;
    }
#pragma unroll
    for (int c = 0; c < 4; ++c) kf[c] = kfn[c];
  }
  ssum += __shfl_xor(ssum, 32);
  float inv = 1.0f / ssum;

  // ================= pass 2: attn write + PV =================
  f32x16 oacc0 = {}, oacc1 = {};
  short8 vf[4], vfn[4];
  {
    int kr0 = ql;
#pragma unroll
    for (int c = 0; c < 4; ++c)
      kf[c] = *(const short8*)&kbase[(size_t)kr0 * 64 + 16 * c + 8 * h];
#pragma unroll
    for (int t = 0; t < 2; ++t)
#pragma unroll
      for (int c2 = 0; c2 < 2; ++c2)
        vf[t * 2 + c2] = *(const short8*)&vbase[(size_t)(32 * t + ql) * VROW + 16 * c2 + 8 * h];
  }
  float* arow = &attn[((size_t)bh * NTOK + qc) * NTOK];

  for (int kt = 0; kt < 2016; kt += 32) {
    {
      int ktn = (kt + 32 < 2016) ? kt + 32 : 0;
      int kr = ktn + ql; if (kr >= NTOK) kr = NTOK - 1;
#pragma unroll
      for (int c = 0; c < 4; ++c)
        kfn[c] = *(const short8*)&kbase[(size_t)kr * 64 + 16 * c + 8 * h];
#pragma unroll
      for (int t = 0; t < 2; ++t)
#pragma unroll
        for (int c2 = 0; c2 < 2; ++c2)
          vfn[t * 2 + c2] = *(const short8*)&vbase[(size_t)(32 * t + ql) * VROW + ktn + 16 * c2 + 8 * h];
    }
    f32x16 acc = {};
#pragma unroll
    for (int c = 0; c < 4; ++c)
      acc = __builtin_amdgcn_mfma_f32_32x32x16_bf16(kf[c], qf[c], acc, 0, 0, 0);
    bool mayPatch = (kt < band_hi) && (kt + 32 > band_lo);
    float e[16];
#pragma unroll
    for (int r = 0; r < 16; ++r) {
      int kc = kt + (r & 3) + 8 * (r >> 2) + 4 * h;
      float sc = acc[r];
      if (mayPatch) {
        if (qa >= 0 && kc < 2000 && (kc / 10) == qa)
          sc = sfb[qa * 100 + (qg - qa * 10) * 10 + (kc - qa * 10)];
      }
      e[r] = (kc < NTOK) ? __expf(sc) : 0.f;
    }
    // ---- attn write (normalized) ----
    if (qok) {
#pragma unroll
      for (int rq = 0; rq < 4; ++rq) {
        int col0 = kt + 8 * rq + 4 * h;
        if (col0 + 3 < NTOK) {
          float4a w = {e[4 * rq] * inv, e[4 * rq + 1] * inv,
                       e[4 * rq + 2] * inv, e[4 * rq + 3] * inv};
          *(float4a*)&arow[col0] = w;
        } else {
#pragma unroll
          for (int j = 0; j < 4; ++j)
            if (col0 + j < NTOK) arow[col0 + j] = e[4 * rq + j] * inv;
        }
      }
    }
    // ---- P -> bf16 B-fragments (unnormalized; O normalized at end) ----
    u32 u00 = pk2(e[0], e[1]),  u01 = pk2(e[2], e[3]);
    u32 u10 = pk2(e[4], e[5]),  u11 = pk2(e[6], e[7]);
    u32 u20 = pk2(e[8], e[9]),  u21 = pk2(e[10], e[11]);
    u32 u30 = pk2(e[12], e[13]), u31 = pk2(e[14], e[15]);
    u32 p00 = __shfl_xor(u00, 32), p01 = __shfl_xor(u01, 32);
    u32 p10 = __shfl_xor(u10, 32), p11 = __shfl_xor(u11, 32);
    u32 p20 = __shfl_xor(u20, 32), p21 = __shfl_xor(u21, 32);
    u32 p30 = __shfl_xor(u30, 32), p31 = __shfl_xor(u31, 32);
    u32 b0[4], b1[4];
    b0[0] = h ? p10 : u00;  b0[1] = h ? p11 : u01;
    b0[2] = h ? u10 : p00;  b0[3] = h ? u11 : p01;
    b1[0] = h ? p30 : u20;  b1[1] = h ? p31 : u21;
    b1[2] = h ? u30 : p20;  b1[3] = h ? u31 : p21;
    short8 B0, B1;
    __builtin_memcpy(&B0, b0, 16);
    __builtin_memcpy(&B1, b1, 16);
    // ---- PV: O^T[d][q] ----
    oacc0 = __builtin_amdgcn_mfma_f32_32x32x16_bf16(vf[0], B0, oacc0, 0, 0, 0);
    oacc1 = __builtin_amdgcn_mfma_f32_32x32x16_bf16(vf[2], B0, oacc1, 0, 0, 0);
    oacc0 = __builtin_amdgcn_mfma_f32_32x32x16_bf16(vf[1], B1, oacc0, 0, 0, 0);
    oacc1 = __builtin_amdgcn_mfma_f32_32x32x16_bf16(vf[3], B1, oacc1, 0, 0, 0);
#pragma unroll
    for (int c = 0; c < 4; ++c) { kf[c] = kfn[c]; vf[c] = vfn[c]; }
  }

  // ---- O writeout (normalize by inv) ----
  if (qok) {
    int b_ = bh >> 2, hd = bh & 3;
    u16* orow = &Ob[((size_t)(b_ * NTOK + qg)) * 256 + hd * 64];
#pragma unroll
    for (int rq = 0; rq < 4; ++rq) {
      int d0a = 8 * rq + 4 * h;
      u32 w0 = pk2(oacc0[4 * rq] * inv, oacc0[4 * rq + 1] * inv);
      u32 w1 = pk2(oacc0[4 * rq + 2] * inv, oacc0[4 * rq + 3] * inv);
      *(uint2*)&orow[d0a] = make_uint2(w0, w1);
      u32 w2 = pk2(oacc1[4 * rq] * inv, oacc1[4 * rq + 1] * inv);
      u32 w3 = pk2(oacc1[4 * rq + 2] * inv, oacc1[4 * rq + 3] * inv);
      *(uint2*)&orow[d0a + 32] = make_uint2(w2, w3);
    }
  }
}

// ---------------- output GEMM: [8036,256] x [1024,256]^T + bias ----------------
__global__ __launch_bounds__(256) void k_gemm_out(
    const u16* __restrict__ A, const u16* __restrict__ Bt,
    const float* __restrict__ bias, float* __restrict__ C)
{
  const int K = 256;
  __shared__ u16 Al[64][72];
  __shared__ u16 Bl[64][72];
  int mt = blockIdx.x * 64, nt = blockIdx.y * 64;
  int tid = threadIdx.x; int lane = tid & 63, wave = tid >> 6;
  int fr = lane & 15, fk = (lane >> 4) * 8;
  f32x4 acc[4];
#pragma unroll
  for (int i = 0; i < 4; ++i) acc[i] = (f32x4){0.f, 0.f, 0.f, 0.f};
  for (int kt = 0; kt < K; kt += 64) {
#pragma unroll
    for (int r = 0; r < 2; ++r) {
      int c = tid + r * 256;
      int row = c >> 3, ch = (c & 7) * 8;
      int am = mt + row; if (am >= M8) am = 0;
      *(short8*)&Al[row][ch] = *(const short8*)&A[(size_t)am * K + kt + ch];
      *(short8*)&Bl[row][ch] = *(const short8*)&Bt[(size_t)(nt + row) * K + kt + ch];
    }
    __syncthreads();
#pragma unroll
    for (int cs = 0; cs < 2; ++cs) {
      short8 bfr = *(const short8*)&Bl[wave * 16 + fr][cs * 32 + fk];
#pragma unroll
      for (int mi = 0; mi < 4; ++mi) {
        short8 afr = *(const short8*)&Al[mi * 16 + fr][cs * 32 + fk];
        acc[mi] = __builtin_amdgcn_mfma_f32_16x16x32_bf16(afr, bfr, acc[mi], 0, 0, 0);
      }
    }
    __syncthreads();
  }
  int n = nt + wave * 16 + fr;
  float bn = bias[n];
#pragma unroll
  for (int mi = 0; mi < 4; ++mi) {
#pragma unroll
    for (int i = 0; i < 4; ++i) {
      int m = mt + mi * 16 + (lane >> 4) * 4 + i;
      if (m < M8) C[(size_t)m * DMOD + n] = acc[mi][i] + bn;
    }
  }
}

extern "C" void kernel_launch(void* const* d_in, const int* in_sizes, int n_in,
                              void* d_out, int out_size, void* d_ws, size_t ws_size,
                              hipStream_t stream) {
  (void)in_sizes; (void)n_in; (void)out_size; (void)ws_size;
  const float* x    = (const float*)d_in[0];
  const float* Wqkv = (const float*)d_in[1];
  const float* Wqs  = (const float*)d_in[2];
  const float* Wout = (const float*)d_in[3];
  const float* bout = (const float*)d_in[4];
  float* out  = (float*)d_out;
  float* attn = out + (size_t)M8 * DMOD;

  char* ws = (char*)d_ws;
  u16*   xb    = (u16*)(ws);
  u16*   WtCat = (u16*)(ws + 16457728);
  u16*   WtOut = (u16*)(ws + 19079168);
  u16*   Qb    = (u16*)(ws + 19603456);
  u16*   Kb    = (u16*)(ws + 23717888);
  u16*   Qsb   = (u16*)(ws + 27832320);
  u16*   Ksb   = (u16*)(ws + 31946752);
  u16*   Vt    = (u16*)(ws + 36061184);
  u16*   Ob    = (u16*)(ws + 40189952);
  float* selfS = (float*)(ws + 44304384);

  k_conv_x<<<dim3(8036), dim3(256), 0, stream>>>(x, xb);
  k_conv_wcat<<<dim3(5120), dim3(256), 0, stream>>>(Wqkv, Wqs, WtCat);
  k_conv_wout<<<dim3(1024), dim3(256), 0, stream>>>(Wout, WtOut);
  k_gemm_proj<<<dim3(126, 20), dim3(256), 0, stream>>>(xb, WtCat, Qb, Kb, Vt, Qsb, Ksb);
  k_self<<<dim3(3200), dim3(128), 0, stream>>>(Qsb, Ksb, selfS);
  k_attn2<<<dim3(16, 63), dim3(64), 0, stream>>>(Qb, Kb, Vt, selfS, attn, Ob);
  k_gemm_out<<<dim3(126, 16), dim3(256), 0, stream>>>(Ob, WtOut, bout, out);
}